// Round 1
// baseline (119.093 us; speedup 1.0000x reference)
//
#include <hip/hip_runtime.h>
#include <math.h>

#define NT 256  // threads per block (one block per theta)

__global__ __launch_bounds__(NT) void wf_kernel(
    const float* __restrict__ xp, const float* __restrict__ yp,
    const float* __restrict__ SOS, const float* __restrict__ x_vec,
    const float* __restrict__ y_vec, const float* __restrict__ thetas,
    const float* __restrict__ Rp, const float* __restrict__ v0p,
    float* __restrict__ out, int n_grid, int n_theta, int n_int)
{
    const int t   = blockIdx.x;
    const int tid = threadIdx.x;
    if (t >= n_theta) return;

    const float x  = xp[0];
    const float y  = yp[0];
    const float R  = Rp[0];
    const float v0 = v0p[0];
    const float th = thetas[t];

    const float x0    = x_vec[0];
    const float dxg   = x_vec[1] - x_vec[0];
    const float ylast = y_vec[n_grid - 1];
    const float dyg   = y_vec[1] - y_vec[0];

    // Per-ray geometry (reference: phi = arctan2(x, y) -- note arg order)
    const float r   = sqrtf(x * x + y * y);
    const float phi = atan2f(x, y);
    float sdp, cdp;
    sincosf(th - phi, &sdp, &cdp);          // sin/cos(th - phi)
    const float s    = r * sdp;
    const float c    = r * cdp;
    const float disc = R * R - s * s;
    const float l_in = sqrtf(fmaxf(disc, 0.0f)) + c;
    // mask = (cos(phi - th) >= 0) & (R >= |s|); cos(phi-th) == cos(th-phi)
    const bool  mask  = (cdp >= 0.0f) && (R >= fabsf(s));
    const float l_out = mask ? l_in : 0.0f;  // sqrt(max(disc*mask,0)) + c*mask
    const float l     = (r < R) ? l_in : l_out;

    float sth, cth;
    sincosf(th, &sth, &cth);

    const float inv = 1.0f / (float)(n_int - 1);   // steps spacing; also seg/l

    // wf = (l * inv) * sum_k w_k * f_k,  w = 0.5 at the two endpoints else 1
    float acc = 0.0f;
    for (int k = tid; k < n_int; k += NT) {
        float step = (float)k * inv;
        float ls   = l * step;
        float xs   = x - ls * sth;
        float ys   = y - ls * cth;
        int j = (int)rintf((xs - x0) / dxg);        // round-half-even == jnp.round
        int i = (int)rintf(-(ys - ylast) / dyg);
        j = min(max(j, 0), n_grid - 1);
        i = min(max(i, 0), n_grid - 1);
        float f = 1.0f - v0 / SOS[(size_t)i * (size_t)n_grid + (size_t)j];
        float w = (k == 0 || k == n_int - 1) ? 0.5f : 1.0f;
        acc += w * f;
    }

    // Wave (64-lane) shuffle reduction, then cross-wave via LDS
    #pragma unroll
    for (int off = 32; off > 0; off >>= 1)
        acc += __shfl_down(acc, off, 64);

    __shared__ float wsum[NT / 64];
    const int wave = tid >> 6;
    const int lane = tid & 63;
    if (lane == 0) wsum[wave] = acc;
    __syncthreads();

    if (tid == 0) {
        float total = 0.0f;
        #pragma unroll
        for (int w = 0; w < NT / 64; ++w) total += wsum[w];
        out[n_theta + t] = total * l * inv;  // wf
        out[t]           = th;               // first tuple element: thetas passthrough
    }
}

extern "C" void kernel_launch(void* const* d_in, const int* in_sizes, int n_in,
                              void* d_out, int out_size, void* d_ws, size_t ws_size,
                              hipStream_t stream) {
    const float* xp     = (const float*)d_in[0];
    const float* yp     = (const float*)d_in[1];
    const float* SOS    = (const float*)d_in[2];
    const float* x_vec  = (const float*)d_in[3];
    const float* y_vec  = (const float*)d_in[4];
    const float* thetas = (const float*)d_in[5];
    const float* Rp     = (const float*)d_in[6];
    const float* v0p    = (const float*)d_in[7];
    float* out = (float*)d_out;

    const int n_grid  = in_sizes[3];   // 4096
    const int n_theta = in_sizes[5];   // 2048
    const int n_int   = 4096;          // N_INT from the reference

    wf_kernel<<<n_theta, NT, 0, stream>>>(xp, yp, SOS, x_vec, y_vec, thetas,
                                          Rp, v0p, out, n_grid, n_theta, n_int);
}

// Round 2
// 117.788 us; speedup vs baseline: 1.0111x; 1.0111x over previous
//
#include <hip/hip_runtime.h>
#include <math.h>

#define NT 256          // threads per block (one block per theta)
#define N_INT_C 4096    // N_INT from the reference
#define ITERS (N_INT_C / NT)  // 16, fully unrolled

__global__ __launch_bounds__(NT) void wf_kernel(
    const float* __restrict__ xp, const float* __restrict__ yp,
    const float* __restrict__ SOS, const float* __restrict__ x_vec,
    const float* __restrict__ y_vec, const float* __restrict__ thetas,
    const float* __restrict__ Rp, const float* __restrict__ v0p,
    float* __restrict__ out, int n_grid, int n_theta)
{
    // XCD-locality swizzle: block bid -> XCD (bid % 8) under round-robin
    // dispatch. Map so each XCD gets a contiguous 1/8 wedge of thetas:
    // adjacent rays share cells (all rays start at the same point), so the
    // wedge working set (~5 MB) approaches one XCD's 4 MiB L2.
    int bid = blockIdx.x;
    int t;
    if ((n_theta & 7) == 0) {
        int chunk = n_theta >> 3;
        t = (bid & 7) * chunk + (bid >> 3);
    } else {
        t = bid;
    }
    const int tid = threadIdx.x;
    if (t >= n_theta) return;

    const float x  = xp[0];
    const float y  = yp[0];
    const float R  = Rp[0];
    const float v0 = v0p[0];
    const float th = thetas[t];

    const float x0    = x_vec[0];
    const float dxg   = x_vec[1] - x_vec[0];
    const float ylast = y_vec[n_grid - 1];
    const float dyg   = y_vec[1] - y_vec[0];

    // Per-ray geometry (reference: phi = arctan2(x, y) -- note arg order)
    const float r   = sqrtf(x * x + y * y);
    const float phi = atan2f(x, y);
    float sdp, cdp;
    sincosf(th - phi, &sdp, &cdp);
    const float s    = r * sdp;
    const float c    = r * cdp;
    const float disc = R * R - s * s;
    const float l_in = sqrtf(fmaxf(disc, 0.0f)) + c;
    const bool  mask  = (cdp >= 0.0f) && (R >= fabsf(s));
    const float l_out = mask ? l_in : 0.0f;
    const float l     = (r < R) ? l_in : l_out;

    float sth, cth;
    sincosf(th, &sth, &cth);

    const float inv   = 1.0f / (float)(N_INT_C - 1);
    const float lstep = l * inv;                  // distance per sample step

    // j = rint((x - l*step*sth - x0)/dxg)      = rint(A - k*P)
    // i = rint((ylast - (y - l*step*cth))/dyg) = rint(C + k*Q)
    const float A = (x - x0) / dxg;
    const float P = lstep * sth / dxg;
    const float C = (ylast - y) / dyg;
    const float Q = lstep * cth / dyg;

    const int gmax = n_grid - 1;

    float acc = 0.0f;
    #pragma unroll
    for (int u = 0; u < ITERS; ++u) {
        const int k = u * NT + tid;               // wave-adjacent lanes -> adjacent samples
        const float fk = (float)k;
        int j = (int)rintf(fmaf(-P, fk, A));
        int i = (int)rintf(fmaf( Q, fk, C));
        j = min(max(j, 0), gmax);
        i = min(max(i, 0), gmax);
        float sos = SOS[i * n_grid + j];
        float f = fmaf(-v0, __builtin_amdgcn_rcpf(sos), 1.0f);
        float w = (k == 0 || k == N_INT_C - 1) ? 0.5f : 1.0f;
        acc += w * f;
    }

    // Wave (64-lane) shuffle reduction, then cross-wave via LDS
    #pragma unroll
    for (int off = 32; off > 0; off >>= 1)
        acc += __shfl_down(acc, off, 64);

    __shared__ float wsum[NT / 64];
    const int wave = tid >> 6;
    const int lane = tid & 63;
    if (lane == 0) wsum[wave] = acc;
    __syncthreads();

    if (tid == 0) {
        float total = 0.0f;
        #pragma unroll
        for (int w = 0; w < NT / 64; ++w) total += wsum[w];
        out[n_theta + t] = total * lstep;   // wf
        out[t]           = th;              // thetas passthrough (tuple elem 0)
    }
}

extern "C" void kernel_launch(void* const* d_in, const int* in_sizes, int n_in,
                              void* d_out, int out_size, void* d_ws, size_t ws_size,
                              hipStream_t stream) {
    const float* xp     = (const float*)d_in[0];
    const float* yp     = (const float*)d_in[1];
    const float* SOS    = (const float*)d_in[2];
    const float* x_vec  = (const float*)d_in[3];
    const float* y_vec  = (const float*)d_in[4];
    const float* thetas = (const float*)d_in[5];
    const float* Rp     = (const float*)d_in[6];
    const float* v0p    = (const float*)d_in[7];
    float* out = (float*)d_out;

    const int n_grid  = in_sizes[3];   // 4096
    const int n_theta = in_sizes[5];   // 2048

    wf_kernel<<<n_theta, NT, 0, stream>>>(xp, yp, SOS, x_vec, y_vec, thetas,
                                          Rp, v0p, out, n_grid, n_theta);
}